// Round 11
// baseline (354.488 us; speedup 1.0000x reference)
//
#include <hip/hip_runtime.h>

// SOM BMU: argmin_m (w_sq[m] - 2*dot(x,w[m])) -> (idx/128, idx%128).
// Single-pass filter + exact rescore:
//   hh (f16-hi) MFMA GEMM (round-9 proven shape: 128x128 coltile, 4 waves,
//   BK=64, 64KB dbuf, 2 blocks/CU). Per coltile: running per-row min +
//   collect candidates within MARGIN into BLOCK-LOCAL LDS lists (no global
//   atomics -- round-10 lesson). Block end: plain dump of cnt+list.
//   Rescore: per-row wave, list-global hh-min, prune by MARGIN, exact fp32
//   wave-dot of ~2-5 survivors. Overflowed chunks (cnt>CAP2, rare) get an
//   exact 1024-col scan -> certified correctness.
// Margin cert: |s_hh - s_true| <= 2*(2*2^-11*||x||*||w||) <= 0.74 < 1.0.

#define B_ROWS 4096
#define M_COLS 16384
#define KF 256
#define BM 128
#define NCHUNK 16
#define NSTEP 32          // 8 coltiles * 4 k-steps (BK=64)
#define CAP2 12
#define MARGIN 1.0f

typedef _Float16 f16x8 __attribute__((ext_vector_type(8)));
typedef float f32x4 __attribute__((ext_vector_type(4)));
typedef unsigned long long u64;

#define GLOAD16(gsrc, ldst) \
  __builtin_amdgcn_global_load_lds((const __attribute__((address_space(1))) void*)(gsrc), \
                                   (__attribute__((address_space(3))) void*)(ldst), 16, 0, 0)

// tile-major: tiles of 128 rows; per (tile,ks32): [kch=4][r=128][8] halves = 8KB
__device__ __forceinline__ size_t tm_idx(int tile, int ks, int kch, int r) {
    return ((((size_t)(tile * 8 + ks)) * 4 + kch) * 128 + r) * 8;
}

__device__ __forceinline__ unsigned fkey(float s) {
    const unsigned fb = __float_as_uint(s);
    return (fb & 0x80000000u) ? ~fb : (fb | 0x80000000u);
}
__device__ __forceinline__ float unkey(unsigned k) {
    return (k & 0x80000000u) ? __uint_as_float(k & 0x7fffffffu) : __uint_as_float(~k);
}

// ---------------- kernel 1: split X -> tile-major f16 hi ----------------
__global__ __launch_bounds__(256) void som_split_x(const float* __restrict__ xb,
                                                   _Float16* __restrict__ xh) {
    const int gid = blockIdx.x * 256 + threadIdx.x;
    const int row = gid >> 5;
    const int kg = gid & 31;
    const float4 v0 = *reinterpret_cast<const float4*>(xb + (size_t)row * KF + kg * 8);
    const float4 v1 = *reinterpret_cast<const float4*>(xb + (size_t)row * KF + kg * 8 + 4);
    const float vv[8] = {v0.x, v0.y, v0.z, v0.w, v1.x, v1.y, v1.z, v1.w};
    f16x8 h;
#pragma unroll
    for (int j = 0; j < 8; ++j) h[j] = (_Float16)vv[j];
    *reinterpret_cast<f16x8*>(xh + tm_idx(row >> 7, kg >> 2, kg & 3, row & 127)) = h;
}

// ---------------- kernel 2: split W -> tile-major f16 hi + w_sq ----------------
__global__ __launch_bounds__(256) void som_split_w(const float* __restrict__ wt,
                                                   _Float16* __restrict__ wh,
                                                   float* __restrict__ wsq) {
    const int gid = blockIdx.x * 256 + threadIdx.x;
    const int row = gid >> 5;
    const int kg = gid & 31;
    const float4 v0 = *reinterpret_cast<const float4*>(wt + (size_t)row * KF + kg * 8);
    const float4 v1 = *reinterpret_cast<const float4*>(wt + (size_t)row * KF + kg * 8 + 4);
    const float vv[8] = {v0.x, v0.y, v0.z, v0.w, v1.x, v1.y, v1.z, v1.w};
    f16x8 h;
    float s = 0.0f;
#pragma unroll
    for (int j = 0; j < 8; ++j) {
        h[j] = (_Float16)vv[j];
        s += vv[j] * vv[j];
    }
    *reinterpret_cast<f16x8*>(wh + tm_idx(row >> 7, kg >> 2, kg & 3, row & 127)) = h;
#pragma unroll
    for (int off = 16; off > 0; off >>= 1) s += __shfl_down(s, off, 64);
    if (kg == 0) wsq[row] = s;   // lanes 0 and 32 each own a row
}

// ---------------- kernel 3: hh GEMM + LDS-local running-min collect ----------------
__global__ __launch_bounds__(256, 2) void som_main(const _Float16* __restrict__ xh,
                                                   const _Float16* __restrict__ wh,
                                                   const float* __restrict__ wsq,
                                                   unsigned* __restrict__ pcnt,
                                                   u64* __restrict__ plist) {
    __shared__ _Float16 lds[2][2][8192];   // 64 KB dbuf
    __shared__ u64 clist[BM][CAP2];        // 12 KB block-local candidate lists
    __shared__ unsigned ccnt[BM];          // 512 B

    const int tid = threadIdx.x;
    const int lane = tid & 63;
    const int frow = lane & 15;
    const int kch = lane >> 4;
    const int wid = tid >> 6;
    const int wr = wid >> 1;      // wave row (0..1): 64 rows
    const int wc = wid & 1;       // wave col (0..1): 64 cols

    // bijective XCD swizzle (512 blocks, 512%8==0)
    const int id = blockIdx.x;
    const int swz = (id & 7) * 64 + (id >> 3);
    const int bx = swz & 31;      // row tile (0..31)
    const int by = swz >> 5;      // col chunk (0..15)
    const int rowbase = bx * BM;

    const int ebase = (tid & 192) * 8;   // wave-uniform LDS base (halves)
    const int tid8 = tid * 8;

    if (tid < BM) ccnt[tid] = 0u;

    float rowbest[16];
#pragma unroll
    for (int i = 0; i < 16; ++i) rowbest[i] = 3.4e38f;

    f32x4 acc[4][4];

#define STAGE(buf_, step_) do {                                               \
    const int ct_ = (step_) >> 2, t_ = (step_) & 3;                           \
    const size_t ab_ = (size_t)(bx * 8 + 2 * t_) * 4096;                      \
    const size_t bb_ = (size_t)((by * 8 + ct_) * 8 + 2 * t_) * 4096;          \
    GLOAD16(xh + ab_ + tid8,        &lds[buf_][0][ebase]);                    \
    GLOAD16(xh + ab_ + 2048 + tid8, &lds[buf_][0][2048 + ebase]);             \
    GLOAD16(xh + ab_ + 4096 + tid8, &lds[buf_][0][4096 + ebase]);             \
    GLOAD16(xh + ab_ + 6144 + tid8, &lds[buf_][0][6144 + ebase]);             \
    GLOAD16(wh + bb_ + tid8,        &lds[buf_][1][ebase]);                    \
    GLOAD16(wh + bb_ + 2048 + tid8, &lds[buf_][1][2048 + ebase]);             \
    GLOAD16(wh + bb_ + 4096 + tid8, &lds[buf_][1][4096 + ebase]);             \
    GLOAD16(wh + bb_ + 6144 + tid8, &lds[buf_][1][6144 + ebase]);             \
  } while (0)

    STAGE(0, 0);
    int buf = 0;

    for (int step = 0; step < NSTEP; ++step) {
        __syncthreads();   // stage(step) landed; everyone done reading buf^1
        if (step < NSTEP - 1) STAGE(buf ^ 1, step + 1);

        if ((step & 3) == 0) {
#pragma unroll
            for (int m = 0; m < 4; ++m)
#pragma unroll
                for (int n = 0; n < 4; ++n) acc[m][n] = (f32x4){0.f, 0.f, 0.f, 0.f};
        }

#pragma unroll
        for (int kk = 0; kk < 2; ++kk) {
            f16x8 bh[4];
#pragma unroll
            for (int n = 0; n < 4; ++n)
                bh[n] = *reinterpret_cast<const f16x8*>(
                    &lds[buf][1][kk * 4096 + kch * 1024 + (wc * 64 + n * 16 + frow) * 8]);
#pragma unroll
            for (int m = 0; m < 4; ++m) {
                const f16x8 ah = *reinterpret_cast<const f16x8*>(
                    &lds[buf][0][kk * 4096 + kch * 1024 + (wr * 64 + m * 16 + frow) * 8]);
#pragma unroll
                for (int n = 0; n < 4; ++n)
                    acc[m][n] = __builtin_amdgcn_mfma_f32_16x16x32_f16(ah, bh[n], acc[m][n], 0, 0, 0);
            }
        }

        if ((step & 3) == 3) {
            // coltile epilogue: running row-min + LDS collect.
            // C/D layout: col=lane&15, row=(lane>>4)*4+reg
            const int ct = step >> 2;
            const int cb = by * 1024 + ct * 128 + wc * 64 + frow;
            float wq[4];
#pragma unroll
            for (int n = 0; n < 4; ++n) wq[n] = wsq[cb + n * 16];
#pragma unroll
            for (int i = 0; i < 16; ++i) {
                const int m = i >> 2, r = i & 3;
                float s[4];
#pragma unroll
                for (int n = 0; n < 4; ++n) s[n] = wq[n] - 2.0f * acc[m][n][r];
                float sm = fminf(fminf(s[0], s[1]), fminf(s[2], s[3]));
#pragma unroll
                for (int mk = 1; mk <= 8; mk <<= 1)
                    sm = fminf(sm, __shfl_xor(sm, mk, 64));
                rowbest[i] = fminf(rowbest[i], sm);
                const float thr = rowbest[i] + MARGIN;
                const int rl = wr * 64 + m * 16 + kch * 4 + r;   // local row 0..127
#pragma unroll
                for (int n = 0; n < 4; ++n) {
                    if (s[n] <= thr) {
                        const unsigned slot = atomicAdd(&ccnt[rl], 1u);
                        if (slot < CAP2)
                            clist[rl][slot] = ((u64)fkey(s[n]) << 32) | (unsigned)(cb + n * 16);
                    }
                }
            }
        }
        buf ^= 1;
    }
#undef STAGE

    // ---- dump counts + lists (plain stores, no atomics) ----
    __syncthreads();
    if (tid < BM) pcnt[(size_t)by * B_ROWS + rowbase + tid] = ccnt[tid];
#pragma unroll
    for (int j0 = 0; j0 < (BM * CAP2) / 256; ++j0) {
        const int j = j0 * 256 + tid;
        const int rl = j / CAP2, sl = j % CAP2;
        plist[((size_t)by * B_ROWS + rowbase + rl) * CAP2 + sl] = clist[rl][sl];
    }
}

// ---------------- kernel 4: prune + exact fp32 rescore + decode ----------------
__global__ __launch_bounds__(256) void som_rescore(const float* __restrict__ xb,
                                                   const float* __restrict__ wt,
                                                   const float* __restrict__ wsq,
                                                   const u64* __restrict__ plist,
                                                   const unsigned* __restrict__ pcnt,
                                                   int* __restrict__ out) {
    const int row = (blockIdx.x * 256 + threadIdx.x) >> 6;   // one wave per row
    const int lane = threadIdx.x & 63;
    if (row >= B_ROWS) return;
    const float4 xv = *reinterpret_cast<const float4*>(xb + (size_t)row * KF + lane * 4);

    // per-chunk counts live in lanes 0..15
    unsigned cnt_l = 0;
    if (lane < NCHUNK) cnt_l = pcnt[(size_t)lane * B_ROWS + row];
    unsigned long long ovf = __ballot(lane < NCHUNK && cnt_l > CAP2) & 0xffffull;

    // gather up to 16*CAP2=192 entries (3 sweeps of 64); wave-min key
    u64 ent[3];
    u64 kmin = ~0ull;
#pragma unroll
    for (int sg = 0; sg < 3; ++sg) {
        const int e = sg * 64 + lane;
        const int b = e / CAP2, sl = e % CAP2;
        const unsigned cb = __shfl(cnt_l, b, 64);
        u64 p = ~0ull;
        if (sl < (int)(cb < CAP2 ? cb : CAP2))
            p = plist[((size_t)b * B_ROWS + row) * CAP2 + sl];
        ent[sg] = p;
        if (p < kmin) kmin = p;
    }
#pragma unroll
    for (int mk = 1; mk <= 32; mk <<= 1) {
        const u64 o = __shfl_xor(kmin, mk, 64);
        if (o < kmin) kmin = o;
    }
    const float thr = unkey((unsigned)(kmin >> 32)) + MARGIN;

    u64 best = ~0ull;
#pragma unroll
    for (int sg = 0; sg < 3; ++sg) {
        const bool keep = (ent[sg] != ~0ull) && (unkey((unsigned)(ent[sg] >> 32)) <= thr);
        unsigned long long mask = __ballot(keep);
        while (mask) {
            const int src = __ffsll(mask) - 1;
            mask &= mask - 1;
            const int col = (int)(__shfl(ent[sg], src, 64) & 0xffffffffu);
            const float4 wv = *reinterpret_cast<const float4*>(wt + (size_t)col * KF + lane * 4);
            float d = xv.x * wv.x + xv.y * wv.y + xv.z * wv.z + xv.w * wv.w;
#pragma unroll
            for (int mk = 1; mk <= 32; mk <<= 1) d += __shfl_xor(d, mk, 64);
            const float sc = wsq[col] - 2.0f * d;
            const u64 q = ((u64)fkey(sc) << 32) | (unsigned)col;
            if (q < best) best = q;
        }
    }

    // overflowed chunks (rare): exact scan of that 1024-col chunk
    while (ovf) {
        const int b = __ffsll(ovf) - 1;
        ovf &= ovf - 1;
        for (int col = b * 1024; col < (b + 1) * 1024; ++col) {
            const float4 wv = *reinterpret_cast<const float4*>(wt + (size_t)col * KF + lane * 4);
            float d = xv.x * wv.x + xv.y * wv.y + xv.z * wv.z + xv.w * wv.w;
#pragma unroll
            for (int mk = 1; mk <= 32; mk <<= 1) d += __shfl_xor(d, mk, 64);
            const float sc = wsq[col] - 2.0f * d;
            const u64 q = ((u64)fkey(sc) << 32) | (unsigned)col;
            if (q < best) best = q;
        }
    }

    if (lane == 0) {
        const int idx = (int)(best & 0xffffffffu);
        out[2 * row] = idx >> 7;      // idx / 128
        out[2 * row + 1] = idx & 127; // idx % 128
    }
}

extern "C" void kernel_launch(void* const* d_in, const int* in_sizes, int n_in,
                              void* d_out, int out_size, void* d_ws, size_t ws_size,
                              hipStream_t stream) {
    const float* xb = (const float*)d_in[0];   // [4096, 256] fp32
    const float* wt = (const float*)d_in[1];   // [16384, 256] fp32
    int* out = (int*)d_out;                    // [4096, 2] int32

    char* ws = (char*)d_ws;
    _Float16* xh  = (_Float16*)(ws);                                   // 2 MB
    _Float16* wh  = (_Float16*)(ws + (size_t)2 * 1024 * 1024);         // 8 MB
    float*    wsq = (float*)(ws + (size_t)10 * 1024 * 1024);           // 64 KB
    unsigned* pcnt = (unsigned*)(ws + (size_t)10 * 1024 * 1024 + 65536);   // 256 KB
    u64*     plist = (u64*)(ws + (size_t)11 * 1024 * 1024);                // 6 MB

    som_split_x<<<(B_ROWS * 32) / 256, 256, 0, stream>>>(xb, xh);
    som_split_w<<<(M_COLS * 32) / 256, 256, 0, stream>>>(wt, wh, wsq);
    som_main<<<BM * NCHUNK / 4, 256, 0, stream>>>(xh, wh, wsq, pcnt, plist);
    som_rescore<<<B_ROWS / 4, 256, 0, stream>>>(xb, wt, wsq, plist, pcnt, out);
}

// Round 12
// 163.904 us; speedup vs baseline: 2.1628x; 2.1628x over previous
//
#include <hip/hip_runtime.h>

// SOM BMU: argmin_m (w_sq[m] - 2*dot(x,w[m])) -> (idx/128, idx%128).
// Single-pass hh (f16-hi) MFMA GEMM that outputs EXACT per-chunk best-2
// (register-tracked, no thresholds, no atomics), then exact fp32 rescore:
//   gmin = min over 16 chunks' b1 (exact hh-min). Rescore all listed entries
//   <= gmin+MARGIN. A chunk can hide an unlisted candidate only if its b2
//   <= gmin+MARGIN (>=3 within margin in one chunk, rare) -> col-parallel
//   exact scan of that chunk. Certified: unlisted c has hh(c) >= b2 > thr.
// Margin cert: |s_hh - s_true| <= 2*2^-11*||x||*||w|| ~ 0.32; 2E=0.64 < 1.0.
// GEMM shape (measured 52.3us): 128x128 coltile, 4 waves, BK=64, 64KB dbuf.

#define B_ROWS 4096
#define M_COLS 16384
#define KF 256
#define BM 128
#define NCHUNK 16
#define NSTEP 32          // 8 coltiles * 4 k-steps (BK=64)
#define MARGIN 1.0f

typedef _Float16 f16x8 __attribute__((ext_vector_type(8)));
typedef float f32x4 __attribute__((ext_vector_type(4)));
typedef unsigned long long u64;

#define GLOAD16(gsrc, ldst) \
  __builtin_amdgcn_global_load_lds((const __attribute__((address_space(1))) void*)(gsrc), \
                                   (__attribute__((address_space(3))) void*)(ldst), 16, 0, 0)

// tile-major: tiles of 128 rows; per (tile,ks32): [kch=4][r=128][8] halves = 8KB
__device__ __forceinline__ size_t tm_idx(int tile, int ks, int kch, int r) {
    return ((((size_t)(tile * 8 + ks)) * 4 + kch) * 128 + r) * 8;
}

__device__ __forceinline__ unsigned fkey(float s) {
    const unsigned u = __float_as_uint(s);
    return u ^ ((unsigned)((int)u >> 31) | 0x80000000u);   // monotone total order
}
__device__ __forceinline__ float unkey(unsigned k) {
    return (k & 0x80000000u) ? __uint_as_float(k & 0x7fffffffu) : __uint_as_float(~k);
}

// ---------------- kernel 1: split X -> tile-major f16 hi ----------------
__global__ __launch_bounds__(256) void som_split_x(const float* __restrict__ xb,
                                                   _Float16* __restrict__ xh) {
    const int gid = blockIdx.x * 256 + threadIdx.x;
    const int row = gid >> 5;
    const int kg = gid & 31;
    const float4 v0 = *reinterpret_cast<const float4*>(xb + (size_t)row * KF + kg * 8);
    const float4 v1 = *reinterpret_cast<const float4*>(xb + (size_t)row * KF + kg * 8 + 4);
    const float vv[8] = {v0.x, v0.y, v0.z, v0.w, v1.x, v1.y, v1.z, v1.w};
    f16x8 h;
#pragma unroll
    for (int j = 0; j < 8; ++j) h[j] = (_Float16)vv[j];
    *reinterpret_cast<f16x8*>(xh + tm_idx(row >> 7, kg >> 2, kg & 3, row & 127)) = h;
}

// ---------------- kernel 2: split W -> tile-major f16 hi + w_sq ----------------
__global__ __launch_bounds__(256) void som_split_w(const float* __restrict__ wt,
                                                   _Float16* __restrict__ wh,
                                                   float* __restrict__ wsq) {
    const int gid = blockIdx.x * 256 + threadIdx.x;
    const int row = gid >> 5;
    const int kg = gid & 31;
    const float4 v0 = *reinterpret_cast<const float4*>(wt + (size_t)row * KF + kg * 8);
    const float4 v1 = *reinterpret_cast<const float4*>(wt + (size_t)row * KF + kg * 8 + 4);
    const float vv[8] = {v0.x, v0.y, v0.z, v0.w, v1.x, v1.y, v1.z, v1.w};
    f16x8 h;
    float s = 0.0f;
#pragma unroll
    for (int j = 0; j < 8; ++j) {
        h[j] = (_Float16)vv[j];
        s += vv[j] * vv[j];
    }
    *reinterpret_cast<f16x8*>(wh + tm_idx(row >> 7, kg >> 2, kg & 3, row & 127)) = h;
#pragma unroll
    for (int off = 16; off > 0; off >>= 1) s += __shfl_down(s, off, 64);
    if (kg == 0) wsq[row] = s;   // lanes 0 and 32 each own a row
}

// ---------------- kernel 3: hh GEMM + exact per-chunk best-2 ----------------
__global__ __launch_bounds__(256, 2) void som_main(const _Float16* __restrict__ xh,
                                                   const _Float16* __restrict__ wh,
                                                   const float* __restrict__ wsq,
                                                   u64* __restrict__ plist) {
    __shared__ _Float16 lds[2][2][8192];   // 64 KB dbuf

    const int tid = threadIdx.x;
    const int lane = tid & 63;
    const int frow = lane & 15;
    const int kch = lane >> 4;
    const int wid = tid >> 6;
    const int wr = wid >> 1;      // wave row (0..1): 64 rows
    const int wc = wid & 1;       // wave col (0..1): 64 cols

    // bijective XCD swizzle (512 blocks, 512%8==0)
    const int id = blockIdx.x;
    const int swz = (id & 7) * 64 + (id >> 3);
    const int bx = swz & 31;      // row tile (0..31)
    const int by = swz >> 5;      // col chunk (0..15)
    const int rowbase = bx * BM;

    const int ebase = (tid & 192) * 8;   // wave-uniform LDS base (halves)
    const int tid8 = tid * 8;

    // per-slot best-2 over this thread's 32 cols (4 n x 8 coltiles)
    unsigned b1k[16], b1c[16], b2k[16], b2c[16];
#pragma unroll
    for (int i = 0; i < 16; ++i) { b1k[i] = b2k[i] = 0xFFFFFFFFu; b1c[i] = b2c[i] = 0u; }

    f32x4 acc[4][4];

#define STAGE(buf_, step_) do {                                               \
    const int ct_ = (step_) >> 2, t_ = (step_) & 3;                           \
    const size_t ab_ = (size_t)(bx * 8 + 2 * t_) * 4096;                      \
    const size_t bb_ = (size_t)((by * 8 + ct_) * 8 + 2 * t_) * 4096;          \
    GLOAD16(xh + ab_ + tid8,        &lds[buf_][0][ebase]);                    \
    GLOAD16(xh + ab_ + 2048 + tid8, &lds[buf_][0][2048 + ebase]);             \
    GLOAD16(xh + ab_ + 4096 + tid8, &lds[buf_][0][4096 + ebase]);             \
    GLOAD16(xh + ab_ + 6144 + tid8, &lds[buf_][0][6144 + ebase]);             \
    GLOAD16(wh + bb_ + tid8,        &lds[buf_][1][ebase]);                    \
    GLOAD16(wh + bb_ + 2048 + tid8, &lds[buf_][1][2048 + ebase]);             \
    GLOAD16(wh + bb_ + 4096 + tid8, &lds[buf_][1][4096 + ebase]);             \
    GLOAD16(wh + bb_ + 6144 + tid8, &lds[buf_][1][6144 + ebase]);             \
  } while (0)

    STAGE(0, 0);
    int buf = 0;

    for (int step = 0; step < NSTEP; ++step) {
        __syncthreads();   // stage(step) landed; everyone done reading buf^1
        if (step < NSTEP - 1) STAGE(buf ^ 1, step + 1);

        if ((step & 3) == 0) {
#pragma unroll
            for (int m = 0; m < 4; ++m)
#pragma unroll
                for (int n = 0; n < 4; ++n) acc[m][n] = (f32x4){0.f, 0.f, 0.f, 0.f};
        }

#pragma unroll
        for (int kk = 0; kk < 2; ++kk) {
            f16x8 bh[4];
#pragma unroll
            for (int n = 0; n < 4; ++n)
                bh[n] = *reinterpret_cast<const f16x8*>(
                    &lds[buf][1][kk * 4096 + kch * 1024 + (wc * 64 + n * 16 + frow) * 8]);
#pragma unroll
            for (int m = 0; m < 4; ++m) {
                const f16x8 ah = *reinterpret_cast<const f16x8*>(
                    &lds[buf][0][kk * 4096 + kch * 1024 + (wr * 64 + m * 16 + frow) * 8]);
#pragma unroll
                for (int n = 0; n < 4; ++n)
                    acc[m][n] = __builtin_amdgcn_mfma_f32_16x16x32_f16(ah, bh[n], acc[m][n], 0, 0, 0);
            }
        }

        if ((step & 3) == 3) {
            // coltile epilogue: branchless best-2 insert per (m,r) slot.
            // C/D layout: col=lane&15, row=(lane>>4)*4+reg
            const int ct = step >> 2;
            const int cb = by * 1024 + ct * 128 + wc * 64 + frow;
            float wq[4];
#pragma unroll
            for (int n = 0; n < 4; ++n) wq[n] = wsq[cb + n * 16];
#pragma unroll
            for (int i = 0; i < 16; ++i) {
                const int m = i >> 2, r = i & 3;
#pragma unroll
                for (int n = 0; n < 4; ++n) {
                    const float s = fmaf(-2.0f, acc[m][n][r], wq[n]);
                    const unsigned key = fkey(s);
                    const unsigned col = (unsigned)(cb + n * 16);
                    const bool lt1 = key < b1k[i];
                    const unsigned xk = lt1 ? b1k[i] : key;   // loser of round 1
                    const unsigned xc = lt1 ? b1c[i] : col;
                    b1k[i] = lt1 ? key : b1k[i];
                    b1c[i] = lt1 ? col : b1c[i];
                    const bool lt2 = xk < b2k[i];
                    b2k[i] = lt2 ? xk : b2k[i];
                    b2c[i] = lt2 ? xc : b2c[i];
                }
            }
        }
        buf ^= 1;
    }
#undef STAGE

    // ---- merge best-2 across the 16 frow lanes (sorted-pair butterfly) ----
#pragma unroll
    for (int mk = 1; mk <= 8; mk <<= 1) {
#pragma unroll
        for (int i = 0; i < 16; ++i) {
            const unsigned o1k = __shfl_xor(b1k[i], mk, 64);
            const unsigned o1c = __shfl_xor(b1c[i], mk, 64);
            const unsigned o2k = __shfl_xor(b2k[i], mk, 64);
            const unsigned o2c = __shfl_xor(b2c[i], mk, 64);
            const bool lt = o1k < b1k[i];
            const unsigned n1k = lt ? o1k : b1k[i];
            const unsigned n1c = lt ? o1c : b1c[i];
            const unsigned xk = lt ? b1k[i] : o1k;
            const unsigned xc = lt ? b1c[i] : o1c;
            const bool l2 = o2k < b2k[i];
            const unsigned m2k = l2 ? o2k : b2k[i];
            const unsigned m2c = l2 ? o2c : b2c[i];
            const bool l3 = xk < m2k;
            b1k[i] = n1k; b1c[i] = n1c;
            b2k[i] = l3 ? xk : m2k;
            b2c[i] = l3 ? xc : m2c;
        }
    }

    // ---- cross-wave (wc) merge via LDS, then plain dump ----
    __syncthreads();
    u64* red = reinterpret_cast<u64*>(&lds[0][0][0]);   // [128 rows][2 wc][2] = 4 KB
    if (frow == 0) {
#pragma unroll
        for (int i = 0; i < 16; ++i) {
            const int rl = wr * 64 + (i >> 2) * 16 + kch * 4 + (i & 3);
            red[(rl * 2 + wc) * 2 + 0] = ((u64)b1k[i] << 32) | b1c[i];
            red[(rl * 2 + wc) * 2 + 1] = ((u64)b2k[i] << 32) | b2c[i];
        }
    }
    __syncthreads();
    if (tid < BM) {
        const u64 a1 = red[(tid * 2 + 0) * 2 + 0], a2 = red[(tid * 2 + 0) * 2 + 1];
        const u64 c1 = red[(tid * 2 + 1) * 2 + 0], c2 = red[(tid * 2 + 1) * 2 + 1];
        const u64 n1 = a1 < c1 ? a1 : c1;
        const u64 xx = a1 < c1 ? c1 : a1;
        const u64 mm = a2 < c2 ? a2 : c2;
        const u64 n2 = xx < mm ? xx : mm;
        plist[((size_t)by * B_ROWS + rowbase + tid) * 2 + 0] = n1;
        plist[((size_t)by * B_ROWS + rowbase + tid) * 2 + 1] = n2;
    }
}

// ---------------- kernel 4: prune + exact fp32 rescore + decode ----------------
__global__ __launch_bounds__(256) void som_rescore(const float* __restrict__ xb,
                                                   const float* __restrict__ wt,
                                                   const float* __restrict__ wsq,
                                                   const u64* __restrict__ plist,
                                                   int* __restrict__ out) {
    const int row = (blockIdx.x * 256 + threadIdx.x) >> 6;   // one wave per row
    const int lane = threadIdx.x & 63;
    if (row >= B_ROWS) return;
    const float4 xv = *reinterpret_cast<const float4*>(xb + (size_t)row * KF + lane * 4);

    // lane<32: entry j=(lane&1) of chunk (lane>>1)
    u64 ent = ~0ull;
    if (lane < 32)
        ent = plist[(((size_t)(lane >> 1)) * B_ROWS + row) * 2 + (lane & 1)];

    u64 g = ent;
#pragma unroll
    for (int mk = 1; mk <= 32; mk <<= 1) {
        const u64 o = __shfl_xor(g, mk, 64);
        if (o < g) g = o;
    }
    const float thr = unkey((unsigned)(g >> 32)) + MARGIN;

    const bool keep = (lane < 32) && (unkey((unsigned)(ent >> 32)) <= thr);
    const unsigned long long kmask = __ballot(keep);
    unsigned long long smask = kmask & 0xAAAAAAAAull;   // odd lanes = chunk b2 within thr

    u64 best = ~0ull;
    // exact rescore of listed survivors (serial over ~1-3, wave-parallel dot)
    unsigned long long m = kmask;
    while (m) {
        const int src = __ffsll(m) - 1;
        m &= m - 1;
        const int col = (int)(__shfl(ent, src, 64) & 0xffffffffu);
        const float4 wv = *reinterpret_cast<const float4*>(wt + (size_t)col * KF + lane * 4);
        float d = xv.x * wv.x + xv.y * wv.y + xv.z * wv.z + xv.w * wv.w;
#pragma unroll
        for (int mk = 1; mk <= 32; mk <<= 1) d += __shfl_xor(d, mk, 64);
        const float sc = wsq[col] - 2.0f * d;
        const u64 q = ((u64)fkey(sc) << 32) | (unsigned)col;
        if (q < best) best = q;
    }

    // rare: chunk may hide a 3rd in-margin candidate -> col-parallel exact scan
    while (smask) {
        const int b = (__ffsll(smask) - 1) >> 1;
        smask &= smask - 1;
        for (int c = b * 1024 + lane; c < (b + 1) * 1024; c += 64) {
            float d = 0.0f;
#pragma unroll
            for (int k = 0; k < KF; k += 4) {
                const float4 wv = *reinterpret_cast<const float4*>(wt + (size_t)c * KF + k);
                const float4 xu = *reinterpret_cast<const float4*>(xb + (size_t)row * KF + k);
                d += wv.x * xu.x + wv.y * xu.y + wv.z * xu.z + wv.w * xu.w;
            }
            const float sc = wsq[c] - 2.0f * d;
            const u64 q = ((u64)fkey(sc) << 32) | (unsigned)c;
            if (q < best) best = q;
        }
    }

#pragma unroll
    for (int mk = 1; mk <= 32; mk <<= 1) {
        const u64 o = __shfl_xor(best, mk, 64);
        if (o < best) best = o;
    }
    if (lane == 0) {
        const int idx = (int)(best & 0xffffffffu);
        out[2 * row] = idx >> 7;      // idx / 128
        out[2 * row + 1] = idx & 127; // idx % 128
    }
}

extern "C" void kernel_launch(void* const* d_in, const int* in_sizes, int n_in,
                              void* d_out, int out_size, void* d_ws, size_t ws_size,
                              hipStream_t stream) {
    const float* xb = (const float*)d_in[0];   // [4096, 256] fp32
    const float* wt = (const float*)d_in[1];   // [16384, 256] fp32
    int* out = (int*)d_out;                    // [4096, 2] int32

    char* ws = (char*)d_ws;
    _Float16* xh  = (_Float16*)(ws);                                   // 2 MB
    _Float16* wh  = (_Float16*)(ws + (size_t)2 * 1024 * 1024);         // 8 MB
    float*    wsq = (float*)(ws + (size_t)10 * 1024 * 1024);           // 64 KB
    u64*    plist = (u64*)(ws + (size_t)10 * 1024 * 1024 + 65536);     // 1 MB

    som_split_x<<<(B_ROWS * 32) / 256, 256, 0, stream>>>(xb, xh);
    som_split_w<<<(M_COLS * 32) / 256, 256, 0, stream>>>(wt, wh, wsq);
    som_main<<<BM * NCHUNK / 4, 256, 0, stream>>>(xh, wh, wsq, plist);
    som_rescore<<<B_ROWS / 4, 256, 0, stream>>>(xb, wt, wsq, plist, out);
}

// Round 13
// 80.618 us; speedup vs baseline: 4.3971x; 2.0331x over previous
//
#include <hip/hip_runtime.h>

// SOM BMU: argmin_m (w_sq[m] - 2*dot(x,w[m])) -> (idx/128, idx%128).
// hh (f16-hi) MFMA GEMM emits ONE u32 min-key per (row, chunk, 32-col
// thread-set) -- no lists, no atomics. Rescore: gmin = min of set-minkeys
// (exact hh-min); scan EVERY set with minkey <= gmin+MARGIN (coverage exact
// by construction: any col with key<=thr lives in such a set; ~2-3 sets/row
// empirically), exact fp32 wave-dot per col, u64 (key|col) min -> tie-break
// to lowest index. MARGIN=0.75 ~ 60x observed-RMS hh error (0.012).
// GEMM shape (measured 52.3us, round 9): 128x128 coltile, 4 waves, BK=64,
// 64KB dbuf LDS, acc[4][4]; minkey upkeep = 1 vmin/slot/coltile.

#define B_ROWS 4096
#define M_COLS 16384
#define KF 256
#define BM 128
#define NCHUNK 16
#define NSTEP 32          // 8 coltiles * 4 k-steps (BK=64)
#define MARGIN 0.75f

typedef _Float16 f16x8 __attribute__((ext_vector_type(8)));
typedef float f32x4 __attribute__((ext_vector_type(4)));
typedef unsigned long long u64;

#define GLOAD16(gsrc, ldst) \
  __builtin_amdgcn_global_load_lds((const __attribute__((address_space(1))) void*)(gsrc), \
                                   (__attribute__((address_space(3))) void*)(ldst), 16, 0, 0)

// tile-major: tiles of 128 rows; per (tile,ks32): [kch=4][r=128][8] halves = 8KB
__device__ __forceinline__ size_t tm_idx(int tile, int ks, int kch, int r) {
    return ((((size_t)(tile * 8 + ks)) * 4 + kch) * 128 + r) * 8;
}

__device__ __forceinline__ unsigned fkey(float s) {
    const unsigned u = __float_as_uint(s);
    return u ^ ((unsigned)((int)u >> 31) | 0x80000000u);   // monotone total order
}
__device__ __forceinline__ float unkey(unsigned k) {
    return (k & 0x80000000u) ? __uint_as_float(k & 0x7fffffffu) : __uint_as_float(~k);
}

// ---------------- kernel 1: split X -> tile-major f16 hi ----------------
__global__ __launch_bounds__(256) void som_split_x(const float* __restrict__ xb,
                                                   _Float16* __restrict__ xh) {
    const int gid = blockIdx.x * 256 + threadIdx.x;
    const int row = gid >> 5;
    const int kg = gid & 31;
    const float4 v0 = *reinterpret_cast<const float4*>(xb + (size_t)row * KF + kg * 8);
    const float4 v1 = *reinterpret_cast<const float4*>(xb + (size_t)row * KF + kg * 8 + 4);
    const float vv[8] = {v0.x, v0.y, v0.z, v0.w, v1.x, v1.y, v1.z, v1.w};
    f16x8 h;
#pragma unroll
    for (int j = 0; j < 8; ++j) h[j] = (_Float16)vv[j];
    *reinterpret_cast<f16x8*>(xh + tm_idx(row >> 7, kg >> 2, kg & 3, row & 127)) = h;
}

// ---------------- kernel 2: split W -> tile-major f16 hi + w_sq ----------------
__global__ __launch_bounds__(256) void som_split_w(const float* __restrict__ wt,
                                                   _Float16* __restrict__ wh,
                                                   float* __restrict__ wsq) {
    const int gid = blockIdx.x * 256 + threadIdx.x;
    const int row = gid >> 5;
    const int kg = gid & 31;
    const float4 v0 = *reinterpret_cast<const float4*>(wt + (size_t)row * KF + kg * 8);
    const float4 v1 = *reinterpret_cast<const float4*>(wt + (size_t)row * KF + kg * 8 + 4);
    const float vv[8] = {v0.x, v0.y, v0.z, v0.w, v1.x, v1.y, v1.z, v1.w};
    f16x8 h;
    float s = 0.0f;
#pragma unroll
    for (int j = 0; j < 8; ++j) {
        h[j] = (_Float16)vv[j];
        s += vv[j] * vv[j];
    }
    *reinterpret_cast<f16x8*>(wh + tm_idx(row >> 7, kg >> 2, kg & 3, row & 127)) = h;
#pragma unroll
    for (int off = 16; off > 0; off >>= 1) s += __shfl_down(s, off, 64);
    if (kg == 0) wsq[row] = s;   // lanes 0 and 32 each own a row
}

// ---------------- kernel 3: hh GEMM + per-set min-key ----------------
__global__ __launch_bounds__(256, 2) void som_main(const _Float16* __restrict__ xh,
                                                   const _Float16* __restrict__ wh,
                                                   const float* __restrict__ wsq,
                                                   unsigned* __restrict__ plist) {
    __shared__ _Float16 lds[2][2][8192];   // 64 KB dbuf

    const int tid = threadIdx.x;
    const int lane = tid & 63;
    const int frow = lane & 15;
    const int kch = lane >> 4;
    const int wid = tid >> 6;
    const int wr = wid >> 1;      // wave row (0..1): 64 rows
    const int wc = wid & 1;       // wave col (0..1): 64 cols

    // bijective XCD swizzle (512 blocks, 512%8==0)
    const int id = blockIdx.x;
    const int swz = (id & 7) * 64 + (id >> 3);
    const int bx = swz & 31;      // row tile (0..31)
    const int by = swz >> 5;      // col chunk (0..15)
    const int rowbase = bx * BM;

    const int ebase = (tid & 192) * 8;   // wave-uniform LDS base (halves)
    const int tid8 = tid * 8;

    unsigned b1k[16];             // per-slot min-key over this thread's 32 cols
#pragma unroll
    for (int i = 0; i < 16; ++i) b1k[i] = 0xFFFFFFFFu;

    f32x4 acc[4][4];

#define STAGE(buf_, step_) do {                                               \
    const int ct_ = (step_) >> 2, t_ = (step_) & 3;                           \
    const size_t ab_ = (size_t)(bx * 8 + 2 * t_) * 4096;                      \
    const size_t bb_ = (size_t)((by * 8 + ct_) * 8 + 2 * t_) * 4096;          \
    GLOAD16(xh + ab_ + tid8,        &lds[buf_][0][ebase]);                    \
    GLOAD16(xh + ab_ + 2048 + tid8, &lds[buf_][0][2048 + ebase]);             \
    GLOAD16(xh + ab_ + 4096 + tid8, &lds[buf_][0][4096 + ebase]);             \
    GLOAD16(xh + ab_ + 6144 + tid8, &lds[buf_][0][6144 + ebase]);             \
    GLOAD16(wh + bb_ + tid8,        &lds[buf_][1][ebase]);                    \
    GLOAD16(wh + bb_ + 2048 + tid8, &lds[buf_][1][2048 + ebase]);             \
    GLOAD16(wh + bb_ + 4096 + tid8, &lds[buf_][1][4096 + ebase]);             \
    GLOAD16(wh + bb_ + 6144 + tid8, &lds[buf_][1][6144 + ebase]);             \
  } while (0)

    STAGE(0, 0);
    int buf = 0;

    for (int step = 0; step < NSTEP; ++step) {
        __syncthreads();   // stage(step) landed; everyone done reading buf^1
        if (step < NSTEP - 1) STAGE(buf ^ 1, step + 1);

        if ((step & 3) == 0) {
#pragma unroll
            for (int m = 0; m < 4; ++m)
#pragma unroll
                for (int n = 0; n < 4; ++n) acc[m][n] = (f32x4){0.f, 0.f, 0.f, 0.f};
        }

#pragma unroll
        for (int kk = 0; kk < 2; ++kk) {
            f16x8 bh[4];
#pragma unroll
            for (int n = 0; n < 4; ++n)
                bh[n] = *reinterpret_cast<const f16x8*>(
                    &lds[buf][1][kk * 4096 + kch * 1024 + (wc * 64 + n * 16 + frow) * 8]);
#pragma unroll
            for (int m = 0; m < 4; ++m) {
                const f16x8 ah = *reinterpret_cast<const f16x8*>(
                    &lds[buf][0][kk * 4096 + kch * 1024 + (wr * 64 + m * 16 + frow) * 8]);
#pragma unroll
                for (int n = 0; n < 4; ++n)
                    acc[m][n] = __builtin_amdgcn_mfma_f32_16x16x32_f16(ah, bh[n], acc[m][n], 0, 0, 0);
            }
        }

        if ((step & 3) == 3) {
            // coltile epilogue: per-slot min over 4 cols -> one key-min.
            // C/D layout: col=lane&15, row=(lane>>4)*4+reg
            const int ct = step >> 2;
            const int cb = by * 1024 + ct * 128 + wc * 64 + frow;
            float wq[4];
#pragma unroll
            for (int n = 0; n < 4; ++n) wq[n] = wsq[cb + n * 16];
#pragma unroll
            for (int i = 0; i < 16; ++i) {
                const int m = i >> 2, r = i & 3;
                const float s0 = fmaf(-2.0f, acc[m][0][r], wq[0]);
                const float s1 = fmaf(-2.0f, acc[m][1][r], wq[1]);
                const float s2 = fmaf(-2.0f, acc[m][2][r], wq[2]);
                const float s3 = fmaf(-2.0f, acc[m][3][r], wq[3]);
                const float sm = fminf(fminf(s0, s1), fminf(s2, s3));
                const unsigned key = fkey(sm);
                b1k[i] = key < b1k[i] ? key : b1k[i];
            }
        }
        buf ^= 1;
    }
#undef STAGE

    // dump: one u32 per (row, set) -- plain stores, no atomics
#pragma unroll
    for (int i = 0; i < 16; ++i) {
        const int rowg = rowbase + wr * 64 + (i >> 2) * 16 + kch * 4 + (i & 3);
        plist[((size_t)by * B_ROWS + rowg) * 32 + frow * 2 + wc] = b1k[i];
    }
}

// ---------------- kernel 4: set-scan exact fp32 rescore + decode ----------------
__global__ __launch_bounds__(256) void som_rescore(const float* __restrict__ xb,
                                                   const float* __restrict__ wt,
                                                   const float* __restrict__ wsq,
                                                   const unsigned* __restrict__ plist,
                                                   int* __restrict__ out) {
    const int row = (blockIdx.x * 256 + threadIdx.x) >> 6;   // one wave per row
    const int lane = threadIdx.x & 63;
    if (row >= B_ROWS) return;
    const float4 xv = *reinterpret_cast<const float4*>(xb + (size_t)row * KF + lane * 4);

    // load 512 set-minkeys (8 sweeps of 64); global hh-min
    unsigned mk[8];
    unsigned g = 0xFFFFFFFFu;
#pragma unroll
    for (int sw = 0; sw < 8; ++sw) {
        const int s = sw * 64 + lane;
        mk[sw] = plist[((size_t)(s >> 5) * B_ROWS + row) * 32 + (s & 31)];
        g = mk[sw] < g ? mk[sw] : g;
    }
#pragma unroll
    for (int mkx = 1; mkx <= 32; mkx <<= 1) {
        const unsigned o = __shfl_xor(g, mkx, 64);
        g = o < g ? o : g;
    }
    const unsigned thr_key = fkey(unkey(g) + MARGIN);

    u64 best = ~0ull;
#pragma unroll
    for (int sw = 0; sw < 8; ++sw) {
        unsigned long long mask = __ballot(mk[sw] <= thr_key);
        while (mask) {
            const int src = __ffsll(mask) - 1;
            mask &= mask - 1;
            const int s = sw * 64 + src;
            const int chunk = s >> 5, frs = (s & 31) >> 1, wcs = s & 1;
            // scan the 32 cols of this set: exact fp32 wave-dot each
#pragma unroll
            for (int ct = 0; ct < 8; ++ct) {
#pragma unroll
                for (int n = 0; n < 4; ++n) {
                    const int col = chunk * 1024 + ct * 128 + wcs * 64 + n * 16 + frs;
                    const float4 wv = *reinterpret_cast<const float4*>(wt + (size_t)col * KF + lane * 4);
                    float d = xv.x * wv.x + xv.y * wv.y + xv.z * wv.z + xv.w * wv.w;
#pragma unroll
                    for (int mkx = 1; mkx <= 32; mkx <<= 1) d += __shfl_xor(d, mkx, 64);
                    const float sc = wsq[col] - 2.0f * d;
                    const u64 q = ((u64)fkey(sc) << 32) | (unsigned)col;
                    if (q < best) best = q;
                }
            }
        }
    }

    if (lane == 0) {
        const int idx = (int)(best & 0xffffffffu);
        out[2 * row] = idx >> 7;      // idx / 128
        out[2 * row + 1] = idx & 127; // idx % 128
    }
}

extern "C" void kernel_launch(void* const* d_in, const int* in_sizes, int n_in,
                              void* d_out, int out_size, void* d_ws, size_t ws_size,
                              hipStream_t stream) {
    const float* xb = (const float*)d_in[0];   // [4096, 256] fp32
    const float* wt = (const float*)d_in[1];   // [16384, 256] fp32
    int* out = (int*)d_out;                    // [4096, 2] int32

    char* ws = (char*)d_ws;
    _Float16* xh  = (_Float16*)(ws);                                   // 2 MB
    _Float16* wh  = (_Float16*)(ws + (size_t)2 * 1024 * 1024);         // 8 MB
    float*    wsq = (float*)(ws + (size_t)10 * 1024 * 1024);           // 64 KB
    unsigned* plist = (unsigned*)(ws + (size_t)11 * 1024 * 1024);      // 8 MB

    som_split_x<<<(B_ROWS * 32) / 256, 256, 0, stream>>>(xb, xh);
    som_split_w<<<(M_COLS * 32) / 256, 256, 0, stream>>>(wt, wh, wsq);
    som_main<<<BM * NCHUNK / 4, 256, 0, stream>>>(xh, wh, wsq, plist);
    som_rescore<<<B_ROWS / 4, 256, 0, stream>>>(xb, wt, wsq, plist, out);
}

// Round 14
// 70.662 us; speedup vs baseline: 5.0167x; 1.1409x over previous
//
#include <hip/hip_runtime.h>

// SOM BMU: argmin_m (w_sq[m] - 2*dot(x,w[m])) -> (idx/128, idx%128).
// hh (f16-hi) MFMA GEMM emits per (row, 32-col thread-set) a packed u64:
//   [b1key:32][b2key>>14:18][b1col:14]   (per-thread best-2, no atomics).
// Rescore: gmin = min b1key (exact hh-min), thr = gmin+MARGIN.
//   b1key<=thr -> direct exact fp32 wave-dot of b1col (~3/row).
//   b2(trunc)<=thr -> col c!=b1col has key>=b2k, so scan set's 32 cols
//   (rare ~0.1/row; truncation rounds down -> never misses).
// Margin: |hh-true| <= ~2^-11*||x||*||w|| ~ 0.3 worst; MARGIN=0.75 covers 2E.
// GEMM shape (measured 42.5us r13): 128x128 coltile, 4 waves, BK=64, 64KB dbuf.

#define B_ROWS 4096
#define M_COLS 16384
#define KF 256
#define BM 128
#define NCHUNK 16
#define NSTEP 32          // 8 coltiles * 4 k-steps (BK=64)
#define MARGIN 0.75f

typedef _Float16 f16x8 __attribute__((ext_vector_type(8)));
typedef float f32x4 __attribute__((ext_vector_type(4)));
typedef unsigned long long u64;

#define GLOAD16(gsrc, ldst) \
  __builtin_amdgcn_global_load_lds((const __attribute__((address_space(1))) void*)(gsrc), \
                                   (__attribute__((address_space(3))) void*)(ldst), 16, 0, 0)

// tile-major: tiles of 128 rows; per (tile,ks32): [kch=4][r=128][8] halves = 8KB
__device__ __forceinline__ size_t tm_idx(int tile, int ks, int kch, int r) {
    return ((((size_t)(tile * 8 + ks)) * 4 + kch) * 128 + r) * 8;
}

__device__ __forceinline__ unsigned fkey(float s) {
    const unsigned u = __float_as_uint(s);
    return u ^ ((unsigned)((int)u >> 31) | 0x80000000u);   // monotone total order
}
__device__ __forceinline__ float unkey(unsigned k) {
    return (k & 0x80000000u) ? __uint_as_float(k & 0x7fffffffu) : __uint_as_float(~k);
}

// ---------------- kernel 1: split X -> tile-major f16 hi ----------------
__global__ __launch_bounds__(256) void som_split_x(const float* __restrict__ xb,
                                                   _Float16* __restrict__ xh) {
    const int gid = blockIdx.x * 256 + threadIdx.x;
    const int row = gid >> 5;
    const int kg = gid & 31;
    const float4 v0 = *reinterpret_cast<const float4*>(xb + (size_t)row * KF + kg * 8);
    const float4 v1 = *reinterpret_cast<const float4*>(xb + (size_t)row * KF + kg * 8 + 4);
    const float vv[8] = {v0.x, v0.y, v0.z, v0.w, v1.x, v1.y, v1.z, v1.w};
    f16x8 h;
#pragma unroll
    for (int j = 0; j < 8; ++j) h[j] = (_Float16)vv[j];
    *reinterpret_cast<f16x8*>(xh + tm_idx(row >> 7, kg >> 2, kg & 3, row & 127)) = h;
}

// ---------------- kernel 2: split W -> tile-major f16 hi + w_sq ----------------
__global__ __launch_bounds__(256) void som_split_w(const float* __restrict__ wt,
                                                   _Float16* __restrict__ wh,
                                                   float* __restrict__ wsq) {
    const int gid = blockIdx.x * 256 + threadIdx.x;
    const int row = gid >> 5;
    const int kg = gid & 31;
    const float4 v0 = *reinterpret_cast<const float4*>(wt + (size_t)row * KF + kg * 8);
    const float4 v1 = *reinterpret_cast<const float4*>(wt + (size_t)row * KF + kg * 8 + 4);
    const float vv[8] = {v0.x, v0.y, v0.z, v0.w, v1.x, v1.y, v1.z, v1.w};
    f16x8 h;
    float s = 0.0f;
#pragma unroll
    for (int j = 0; j < 8; ++j) {
        h[j] = (_Float16)vv[j];
        s += vv[j] * vv[j];
    }
    *reinterpret_cast<f16x8*>(wh + tm_idx(row >> 7, kg >> 2, kg & 3, row & 127)) = h;
#pragma unroll
    for (int off = 16; off > 0; off >>= 1) s += __shfl_down(s, off, 64);
    if (kg == 0) wsq[row] = s;   // lanes 0 and 32 each own a row
}

// ---------------- kernel 3: hh GEMM + per-set best-2 (packed u64) ----------------
__global__ __launch_bounds__(256, 2) void som_main(const _Float16* __restrict__ xh,
                                                   const _Float16* __restrict__ wh,
                                                   const float* __restrict__ wsq,
                                                   u64* __restrict__ plist) {
    __shared__ _Float16 lds[2][2][8192];   // 64 KB dbuf

    const int tid = threadIdx.x;
    const int lane = tid & 63;
    const int frow = lane & 15;
    const int kch = lane >> 4;
    const int wid = tid >> 6;
    const int wr = wid >> 1;      // wave row (0..1): 64 rows
    const int wc = wid & 1;       // wave col (0..1): 64 cols

    // bijective XCD swizzle (512 blocks, 512%8==0)
    const int id = blockIdx.x;
    const int swz = (id & 7) * 64 + (id >> 3);
    const int bx = swz & 31;      // row tile (0..31)
    const int by = swz >> 5;      // col chunk (0..15)
    const int rowbase = bx * BM;

    const int ebase = (tid & 192) * 8;   // wave-uniform LDS base (halves)
    const int tid8 = tid * 8;

    unsigned b1k[16], b1c[16], b2k[16];   // per-slot best-2 over this thread's 32 cols
#pragma unroll
    for (int i = 0; i < 16; ++i) { b1k[i] = b2k[i] = 0xFFFFFFFFu; b1c[i] = 0u; }

    f32x4 acc[4][4];

#define STAGE(buf_, step_) do {                                               \
    const int ct_ = (step_) >> 2, t_ = (step_) & 3;                           \
    const size_t ab_ = (size_t)(bx * 8 + 2 * t_) * 4096;                      \
    const size_t bb_ = (size_t)((by * 8 + ct_) * 8 + 2 * t_) * 4096;          \
    GLOAD16(xh + ab_ + tid8,        &lds[buf_][0][ebase]);                    \
    GLOAD16(xh + ab_ + 2048 + tid8, &lds[buf_][0][2048 + ebase]);             \
    GLOAD16(xh + ab_ + 4096 + tid8, &lds[buf_][0][4096 + ebase]);             \
    GLOAD16(xh + ab_ + 6144 + tid8, &lds[buf_][0][6144 + ebase]);             \
    GLOAD16(wh + bb_ + tid8,        &lds[buf_][1][ebase]);                    \
    GLOAD16(wh + bb_ + 2048 + tid8, &lds[buf_][1][2048 + ebase]);             \
    GLOAD16(wh + bb_ + 4096 + tid8, &lds[buf_][1][4096 + ebase]);             \
    GLOAD16(wh + bb_ + 6144 + tid8, &lds[buf_][1][6144 + ebase]);             \
  } while (0)

    STAGE(0, 0);
    int buf = 0;

    for (int step = 0; step < NSTEP; ++step) {
        __syncthreads();   // stage(step) landed; everyone done reading buf^1
        if (step < NSTEP - 1) STAGE(buf ^ 1, step + 1);

        if ((step & 3) == 0) {
#pragma unroll
            for (int m = 0; m < 4; ++m)
#pragma unroll
                for (int n = 0; n < 4; ++n) acc[m][n] = (f32x4){0.f, 0.f, 0.f, 0.f};
        }

#pragma unroll
        for (int kk = 0; kk < 2; ++kk) {
            f16x8 bh[4];
#pragma unroll
            for (int n = 0; n < 4; ++n)
                bh[n] = *reinterpret_cast<const f16x8*>(
                    &lds[buf][1][kk * 4096 + kch * 1024 + (wc * 64 + n * 16 + frow) * 8]);
#pragma unroll
            for (int m = 0; m < 4; ++m) {
                const f16x8 ah = *reinterpret_cast<const f16x8*>(
                    &lds[buf][0][kk * 4096 + kch * 1024 + (wr * 64 + m * 16 + frow) * 8]);
#pragma unroll
                for (int n = 0; n < 4; ++n)
                    acc[m][n] = __builtin_amdgcn_mfma_f32_16x16x32_f16(ah, bh[n], acc[m][n], 0, 0, 0);
            }
        }

        if ((step & 3) == 3) {
            // coltile epilogue: branchless per-slot best-2 insert (no cross-lane).
            // C/D layout: col=lane&15, row=(lane>>4)*4+reg
            const int ct = step >> 2;
            const int cb = by * 1024 + ct * 128 + wc * 64 + frow;
            float wq[4];
#pragma unroll
            for (int n = 0; n < 4; ++n) wq[n] = wsq[cb + n * 16];
#pragma unroll
            for (int i = 0; i < 16; ++i) {
                const int m = i >> 2, r = i & 3;
                const unsigned k0 = fkey(fmaf(-2.0f, acc[m][0][r], wq[0]));
                const unsigned k1 = fkey(fmaf(-2.0f, acc[m][1][r], wq[1]));
                const unsigned k2 = fkey(fmaf(-2.0f, acc[m][2][r], wq[2]));
                const unsigned k3 = fkey(fmaf(-2.0f, acc[m][3][r], wq[3]));
                // best-2 of the 4 (track col only for the best)
                const bool p0 = k0 <= k1;
                const unsigned ka = p0 ? k0 : k1, xa = p0 ? k1 : k0;
                const unsigned ca = p0 ? (unsigned)cb : (unsigned)(cb + 16);
                const bool p1 = k2 <= k3;
                const unsigned kb = p1 ? k2 : k3, xb = p1 ? k3 : k2;
                const unsigned cbv = p1 ? (unsigned)(cb + 32) : (unsigned)(cb + 48);
                const bool p2 = ka <= kb;
                const unsigned kl = p2 ? ka : kb;
                const unsigned cl = p2 ? ca : cbv;
                const unsigned l2 = min(p2 ? kb : ka, min(xa, xb));
                // merge into running best-2
                const bool q = kl < b1k[i];
                const unsigned d = q ? b1k[i] : kl;       // displaced key
                b1c[i] = q ? cl : b1c[i];
                b1k[i] = q ? kl : b1k[i];
                b2k[i] = min(min(d, l2), b2k[i]);
            }
        }
        buf ^= 1;
    }
#undef STAGE

    // dump: one packed u64 per (row, set): [b1k:32][b2k>>14:18][b1col:14]
#pragma unroll
    for (int i = 0; i < 16; ++i) {
        const int rowg = rowbase + wr * 64 + (i >> 2) * 16 + kch * 4 + (i & 3);
        const u64 e = ((u64)b1k[i] << 32) | ((u64)(b2k[i] >> 14) << 14) | (u64)(b1c[i] & 0x3FFFu);
        plist[(size_t)rowg * 512 + by * 32 + frow * 2 + wc] = e;
    }
}

// ---------------- kernel 4: direct rescore + rare set-scan + decode ----------------
__global__ __launch_bounds__(256) void som_rescore(const float* __restrict__ xb,
                                                   const float* __restrict__ wt,
                                                   const float* __restrict__ wsq,
                                                   const u64* __restrict__ plist,
                                                   int* __restrict__ out) {
    const int row = (blockIdx.x * 256 + threadIdx.x) >> 6;   // one wave per row
    const int lane = threadIdx.x & 63;
    if (row >= B_ROWS) return;
    const float4 xv = *reinterpret_cast<const float4*>(xb + (size_t)row * KF + lane * 4);

    // load 512 packed entries (8 sweeps of 64, coalesced); global hh-min over b1k
    u64 ev[8];
    unsigned g = 0xFFFFFFFFu;
#pragma unroll
    for (int sw = 0; sw < 8; ++sw) {
        ev[sw] = plist[(size_t)row * 512 + sw * 64 + lane];
        const unsigned b1 = (unsigned)(ev[sw] >> 32);
        g = b1 < g ? b1 : g;
    }
#pragma unroll
    for (int mkx = 1; mkx <= 32; mkx <<= 1) {
        const unsigned o = __shfl_xor(g, mkx, 64);
        g = o < g ? o : g;
    }
    const unsigned thr_key = fkey(unkey(g) + MARGIN);
    const unsigned thr_t = thr_key >> 14;

    u64 best = ~0ull;
#pragma unroll
    for (int sw = 0; sw < 8; ++sw) {
        const unsigned b1 = (unsigned)(ev[sw] >> 32);
        const unsigned b2t = (unsigned)(ev[sw] >> 14) & 0x3FFFFu;
        const bool scan = b2t <= thr_t;
        // direct rescore of b1col where only b1 is in margin
        unsigned long long mask = __ballot(b1 <= thr_key && !scan);
        while (mask) {
            const int src = __ffsll(mask) - 1;
            mask &= mask - 1;
            const int col = (int)(__shfl(ev[sw], src, 64) & 0x3FFFull);
            const float4 wv = *reinterpret_cast<const float4*>(wt + (size_t)col * KF + lane * 4);
            float d = xv.x * wv.x + xv.y * wv.y + xv.z * wv.z + xv.w * wv.w;
#pragma unroll
            for (int mkx = 1; mkx <= 32; mkx <<= 1) d += __shfl_xor(d, mkx, 64);
            const float sc = wsq[col] - 2.0f * d;
            const u64 q = ((u64)fkey(sc) << 32) | (unsigned)col;
            if (q < best) best = q;
        }
        // rare: 2+ in-margin cols in one set -> exact scan of its 32 cols
        unsigned long long mask2 = __ballot(scan);
        while (mask2) {
            const int src = __ffsll(mask2) - 1;
            mask2 &= mask2 - 1;
            const int s = sw * 64 + src;
            const int chunk = s >> 5, frs = (s & 31) >> 1, wcs = s & 1;
#pragma unroll
            for (int ct = 0; ct < 8; ++ct)
#pragma unroll
                for (int n = 0; n < 4; ++n) {
                    const int col = chunk * 1024 + ct * 128 + wcs * 64 + n * 16 + frs;
                    const float4 wv = *reinterpret_cast<const float4*>(wt + (size_t)col * KF + lane * 4);
                    float d = xv.x * wv.x + xv.y * wv.y + xv.z * wv.z + xv.w * wv.w;
#pragma unroll
                    for (int mkx = 1; mkx <= 32; mkx <<= 1) d += __shfl_xor(d, mkx, 64);
                    const float sc = wsq[col] - 2.0f * d;
                    const u64 q = ((u64)fkey(sc) << 32) | (unsigned)col;
                    if (q < best) best = q;
                }
        }
    }

    if (lane == 0) {
        const int idx = (int)(best & 0xffffffffu);
        out[2 * row] = idx >> 7;      // idx / 128
        out[2 * row + 1] = idx & 127; // idx % 128
    }
}

extern "C" void kernel_launch(void* const* d_in, const int* in_sizes, int n_in,
                              void* d_out, int out_size, void* d_ws, size_t ws_size,
                              hipStream_t stream) {
    const float* xb = (const float*)d_in[0];   // [4096, 256] fp32
    const float* wt = (const float*)d_in[1];   // [16384, 256] fp32
    int* out = (int*)d_out;                    // [4096, 2] int32

    char* ws = (char*)d_ws;
    _Float16* xh  = (_Float16*)(ws);                                   // 2 MB
    _Float16* wh  = (_Float16*)(ws + (size_t)2 * 1024 * 1024);         // 8 MB
    float*    wsq = (float*)(ws + (size_t)10 * 1024 * 1024);           // 64 KB
    u64*    plist = (u64*)(ws + (size_t)11 * 1024 * 1024);             // 16 MB

    som_split_x<<<(B_ROWS * 32) / 256, 256, 0, stream>>>(xb, xh);
    som_split_w<<<(M_COLS * 32) / 256, 256, 0, stream>>>(wt, wh, wsq);
    som_main<<<BM * NCHUNK / 4, 256, 0, stream>>>(xh, wh, wsq, plist);
    som_rescore<<<B_ROWS / 4, 256, 0, stream>>>(xb, wt, wsq, plist, out);
}

// Round 15
// 63.204 us; speedup vs baseline: 5.6086x; 1.1180x over previous
//
#include <hip/hip_runtime.h>

// SOM BMU: argmin_m (w_sq[m] - 2*dot(x,w[m])) -> (idx/128, idx%128).
// hh (f16-hi) MFMA GEMM emits per (row, 32-col thread-set) a packed u64:
//   [b1key:32][b2key>>14:18][b1col:14]  (per-thread best-2, float-domain
//   tracking, fkey only at dump; no atomics).
// Rescore: gmin = min b1key (exact hh-min), thr = gmin+MARGIN.
//   b1key<=thr & b2>thr -> direct exact fp32 wave-dot of b1col (~3/row,
//   processed in pairs with interleaved reduction chains).
//   b2(trunc)<=thr -> scan set's 32 cols, 4 at a time (rare; truncation
//   rounds down -> never misses). Coverage: c!=b1col => key(c)>=b2k.
// Margin: |hh-true| <= ~2^-11*||x||*||w|| ~ 0.3 worst; MARGIN=0.75 covers 2E.
// GEMM shape (r9/r13 measured): 128x128 coltile, 4 waves, BK=64, 64KB dbuf.

#define B_ROWS 4096
#define M_COLS 16384
#define KF 256
#define BM 128
#define NCHUNK 16
#define NSTEP 32          // 8 coltiles * 4 k-steps (BK=64)
#define MARGIN 0.75f

typedef _Float16 f16x8 __attribute__((ext_vector_type(8)));
typedef float f32x4 __attribute__((ext_vector_type(4)));
typedef unsigned long long u64;

#define GLOAD16(gsrc, ldst) \
  __builtin_amdgcn_global_load_lds((const __attribute__((address_space(1))) void*)(gsrc), \
                                   (__attribute__((address_space(3))) void*)(ldst), 16, 0, 0)

// tile-major: tiles of 128 rows; per (tile,ks32): [kch=4][r=128][8] halves = 8KB
__device__ __forceinline__ size_t tm_idx(int tile, int ks, int kch, int r) {
    return ((((size_t)(tile * 8 + ks)) * 4 + kch) * 128 + r) * 8;
}

__device__ __forceinline__ unsigned fkey(float s) {
    const unsigned u = __float_as_uint(s);
    return u ^ ((unsigned)((int)u >> 31) | 0x80000000u);   // monotone total order
}
__device__ __forceinline__ float unkey(unsigned k) {
    return (k & 0x80000000u) ? __uint_as_float(k & 0x7fffffffu) : __uint_as_float(~k);
}

// ---------------- kernel 1: fused split X and W -> tile-major f16 hi (+ w_sq) ----------------
__global__ __launch_bounds__(256) void som_split(const float* __restrict__ xb,
                                                 const float* __restrict__ wt,
                                                 _Float16* __restrict__ xh,
                                                 _Float16* __restrict__ wh,
                                                 float* __restrict__ wsq) {
    const int bid = blockIdx.x;
    const bool isx = bid < (B_ROWS * 32) / 256;
    const int gid = (isx ? bid : bid - (B_ROWS * 32) / 256) * 256 + threadIdx.x;
    const float* src = isx ? xb : wt;
    _Float16* dst = isx ? xh : wh;
    const int row = gid >> 5;
    const int kg = gid & 31;
    const float4 v0 = *reinterpret_cast<const float4*>(src + (size_t)row * KF + kg * 8);
    const float4 v1 = *reinterpret_cast<const float4*>(src + (size_t)row * KF + kg * 8 + 4);
    const float vv[8] = {v0.x, v0.y, v0.z, v0.w, v1.x, v1.y, v1.z, v1.w};
    f16x8 h;
    float s = 0.0f;
#pragma unroll
    for (int j = 0; j < 8; ++j) {
        h[j] = (_Float16)vv[j];
        s += vv[j] * vv[j];
    }
    *reinterpret_cast<f16x8*>(dst + tm_idx(row >> 7, kg >> 2, kg & 3, row & 127)) = h;
    if (!isx) {
#pragma unroll
        for (int off = 16; off > 0; off >>= 1) s += __shfl_down(s, off, 64);
        if (kg == 0) wsq[row] = s;   // lanes 0 and 32 each own a row
    }
}

// ---------------- kernel 2: hh GEMM + per-set best-2 (float-domain) ----------------
__global__ __launch_bounds__(256, 2) void som_main(const _Float16* __restrict__ xh,
                                                   const _Float16* __restrict__ wh,
                                                   const float* __restrict__ wsq,
                                                   u64* __restrict__ plist) {
    __shared__ _Float16 lds[2][2][8192];   // 64 KB dbuf

    const int tid = threadIdx.x;
    const int lane = tid & 63;
    const int frow = lane & 15;
    const int kch = lane >> 4;
    const int wid = tid >> 6;
    const int wr = wid >> 1;      // wave row (0..1): 64 rows
    const int wc = wid & 1;       // wave col (0..1): 64 cols

    // bijective XCD swizzle (512 blocks, 512%8==0)
    const int id = blockIdx.x;
    const int swz = (id & 7) * 64 + (id >> 3);
    const int bx = swz & 31;      // row tile (0..31)
    const int by = swz >> 5;      // col chunk (0..15)
    const int rowbase = bx * BM;

    const int ebase = (tid & 192) * 8;   // wave-uniform LDS base (halves)
    const int tid8 = tid * 8;

    float b1v[16], b2v[16];       // per-slot best-2 scores over this thread's 32 cols
    unsigned b1c[16];
#pragma unroll
    for (int i = 0; i < 16; ++i) { b1v[i] = b2v[i] = 3.4e38f; b1c[i] = 0u; }

    f32x4 acc[4][4];

#define STAGE(buf_, step_) do {                                               \
    const int ct_ = (step_) >> 2, t_ = (step_) & 3;                           \
    const size_t ab_ = (size_t)(bx * 8 + 2 * t_) * 4096;                      \
    const size_t bb_ = (size_t)((by * 8 + ct_) * 8 + 2 * t_) * 4096;          \
    GLOAD16(xh + ab_ + tid8,        &lds[buf_][0][ebase]);                    \
    GLOAD16(xh + ab_ + 2048 + tid8, &lds[buf_][0][2048 + ebase]);             \
    GLOAD16(xh + ab_ + 4096 + tid8, &lds[buf_][0][4096 + ebase]);             \
    GLOAD16(xh + ab_ + 6144 + tid8, &lds[buf_][0][6144 + ebase]);             \
    GLOAD16(wh + bb_ + tid8,        &lds[buf_][1][ebase]);                    \
    GLOAD16(wh + bb_ + 2048 + tid8, &lds[buf_][1][2048 + ebase]);             \
    GLOAD16(wh + bb_ + 4096 + tid8, &lds[buf_][1][4096 + ebase]);             \
    GLOAD16(wh + bb_ + 6144 + tid8, &lds[buf_][1][6144 + ebase]);             \
  } while (0)

    STAGE(0, 0);
    int buf = 0;

    for (int step = 0; step < NSTEP; ++step) {
        __syncthreads();   // stage(step) landed; everyone done reading buf^1
        if (step < NSTEP - 1) STAGE(buf ^ 1, step + 1);

        if ((step & 3) == 0) {
#pragma unroll
            for (int m = 0; m < 4; ++m)
#pragma unroll
                for (int n = 0; n < 4; ++n) acc[m][n] = (f32x4){0.f, 0.f, 0.f, 0.f};
        }

#pragma unroll
        for (int kk = 0; kk < 2; ++kk) {
            f16x8 bh[4];
#pragma unroll
            for (int n = 0; n < 4; ++n)
                bh[n] = *reinterpret_cast<const f16x8*>(
                    &lds[buf][1][kk * 4096 + kch * 1024 + (wc * 64 + n * 16 + frow) * 8]);
#pragma unroll
            for (int m = 0; m < 4; ++m) {
                const f16x8 ah = *reinterpret_cast<const f16x8*>(
                    &lds[buf][0][kk * 4096 + kch * 1024 + (wr * 64 + m * 16 + frow) * 8]);
#pragma unroll
                for (int n = 0; n < 4; ++n)
                    acc[m][n] = __builtin_amdgcn_mfma_f32_16x16x32_f16(ah, bh[n], acc[m][n], 0, 0, 0);
            }
        }

        if ((step & 3) == 3) {
            // coltile epilogue: float-domain branchless best-2 (no fkey here).
            // C/D layout: col=lane&15, row=(lane>>4)*4+reg
            const int ct = step >> 2;
            const int cb = by * 1024 + ct * 128 + wc * 64 + frow;
            float wq[4];
#pragma unroll
            for (int n = 0; n < 4; ++n) wq[n] = wsq[cb + n * 16];
#pragma unroll
            for (int i = 0; i < 16; ++i) {
                const int m = i >> 2, r = i & 3;
                const float s0 = fmaf(-2.0f, acc[m][0][r], wq[0]);
                const float s1 = fmaf(-2.0f, acc[m][1][r], wq[1]);
                const float s2 = fmaf(-2.0f, acc[m][2][r], wq[2]);
                const float s3 = fmaf(-2.0f, acc[m][3][r], wq[3]);
                const float lo01 = fminf(s0, s1), hi01 = fmaxf(s0, s1);
                const float lo23 = fminf(s2, s3), hi23 = fmaxf(s2, s3);
                const unsigned c01 = s0 <= s1 ? (unsigned)cb : (unsigned)(cb + 16);
                const unsigned c23 = s2 <= s3 ? (unsigned)(cb + 32) : (unsigned)(cb + 48);
                const float l1 = fminf(lo01, lo23);
                const unsigned cl = lo01 <= lo23 ? c01 : c23;
                const float l2 = fminf(fminf(hi01, hi23), fmaxf(lo01, lo23));
                const bool q = l1 < b1v[i];
                const float disp = q ? b1v[i] : l1;       // displaced score
                b1c[i] = q ? cl : b1c[i];
                b1v[i] = fminf(l1, b1v[i]);
                b2v[i] = fminf(fminf(disp, l2), b2v[i]);
            }
        }
        buf ^= 1;
    }
#undef STAGE

    // dump: one packed u64 per (row, set): [b1k:32][b2k>>14:18][b1col:14]
#pragma unroll
    for (int i = 0; i < 16; ++i) {
        const int rowg = rowbase + wr * 64 + (i >> 2) * 16 + kch * 4 + (i & 3);
        const u64 e = ((u64)fkey(b1v[i]) << 32) |
                      ((u64)(fkey(b2v[i]) >> 14) << 14) | (u64)(b1c[i] & 0x3FFFu);
        plist[(size_t)rowg * 512 + by * 32 + frow * 2 + wc] = e;
    }
}

// ---------------- kernel 3: direct rescore + rare set-scan + decode ----------------
__global__ __launch_bounds__(256) void som_rescore(const float* __restrict__ xb,
                                                   const float* __restrict__ wt,
                                                   const float* __restrict__ wsq,
                                                   const u64* __restrict__ plist,
                                                   int* __restrict__ out) {
    const int row = (blockIdx.x * 256 + threadIdx.x) >> 6;   // one wave per row
    const int lane = threadIdx.x & 63;
    if (row >= B_ROWS) return;
    const float4 xv = *reinterpret_cast<const float4*>(xb + (size_t)row * KF + lane * 4);

    // load 512 packed entries (8 sweeps of 64, coalesced); global hh-min over b1k
    u64 ev[8];
    unsigned g = 0xFFFFFFFFu;
#pragma unroll
    for (int sw = 0; sw < 8; ++sw) {
        ev[sw] = plist[(size_t)row * 512 + sw * 64 + lane];
        const unsigned b1 = (unsigned)(ev[sw] >> 32);
        g = b1 < g ? b1 : g;
    }
#pragma unroll
    for (int mkx = 1; mkx <= 32; mkx <<= 1) {
        const unsigned o = __shfl_xor(g, mkx, 64);
        g = o < g ? o : g;
    }
    const unsigned thr_key = fkey(unkey(g) + MARGIN);
    const unsigned thr_t = thr_key >> 14;

    u64 best = ~0ull;
#pragma unroll
    for (int sw = 0; sw < 8; ++sw) {
        const unsigned b1 = (unsigned)(ev[sw] >> 32);
        const unsigned b2t = (unsigned)(ev[sw] >> 14) & 0x3FFFFu;
        const bool scan = b2t <= thr_t;
        // direct rescore of b1col (pairs: two independent reduction chains)
        unsigned long long mask = __ballot(b1 <= thr_key && !scan);
        while (mask) {
            const int s0 = __ffsll(mask) - 1; mask &= mask - 1;
            const bool two = mask != 0ull;
            int s1 = s0;
            if (two) { s1 = __ffsll(mask) - 1; mask &= mask - 1; }
            const int col0 = (int)(__shfl(ev[sw], s0, 64) & 0x3FFFull);
            const int col1 = (int)(__shfl(ev[sw], s1, 64) & 0x3FFFull);
            const float4 w0 = *reinterpret_cast<const float4*>(wt + (size_t)col0 * KF + lane * 4);
            float d0 = xv.x * w0.x + xv.y * w0.y + xv.z * w0.z + xv.w * w0.w;
            float d1 = 0.0f;
            if (two) {
                const float4 w1 = *reinterpret_cast<const float4*>(wt + (size_t)col1 * KF + lane * 4);
                d1 = xv.x * w1.x + xv.y * w1.y + xv.z * w1.z + xv.w * w1.w;
            }
#pragma unroll
            for (int mkx = 1; mkx <= 32; mkx <<= 1) {
                d0 += __shfl_xor(d0, mkx, 64);
                d1 += __shfl_xor(d1, mkx, 64);
            }
            const u64 q0 = ((u64)fkey(wsq[col0] - 2.0f * d0) << 32) | (unsigned)col0;
            if (q0 < best) best = q0;
            if (two) {
                const u64 q1 = ((u64)fkey(wsq[col1] - 2.0f * d1) << 32) | (unsigned)col1;
                if (q1 < best) best = q1;
            }
        }
        // rare: 2+ in-margin cols in one set -> exact scan, 4 cols at a time
        unsigned long long mask2 = __ballot(scan);
        while (mask2) {
            const int src = __ffsll(mask2) - 1;
            mask2 &= mask2 - 1;
            const int s = sw * 64 + src;
            const int chunk = s >> 5, frs = (s & 31) >> 1, wcs = s & 1;
#pragma unroll
            for (int ct = 0; ct < 8; ++ct) {
                float d[4];
                int colv[4];
#pragma unroll
                for (int n = 0; n < 4; ++n) {
                    colv[n] = chunk * 1024 + ct * 128 + wcs * 64 + n * 16 + frs;
                    const float4 wv = *reinterpret_cast<const float4*>(wt + (size_t)colv[n] * KF + lane * 4);
                    d[n] = xv.x * wv.x + xv.y * wv.y + xv.z * wv.z + xv.w * wv.w;
                }
#pragma unroll
                for (int mkx = 1; mkx <= 32; mkx <<= 1)
#pragma unroll
                    for (int n = 0; n < 4; ++n) d[n] += __shfl_xor(d[n], mkx, 64);
#pragma unroll
                for (int n = 0; n < 4; ++n) {
                    const u64 q = ((u64)fkey(wsq[colv[n]] - 2.0f * d[n]) << 32) | (unsigned)colv[n];
                    if (q < best) best = q;
                }
            }
        }
    }

    if (lane == 0) {
        const int idx = (int)(best & 0xffffffffu);
        out[2 * row] = idx >> 7;      // idx / 128
        out[2 * row + 1] = idx & 127; // idx % 128
    }
}

extern "C" void kernel_launch(void* const* d_in, const int* in_sizes, int n_in,
                              void* d_out, int out_size, void* d_ws, size_t ws_size,
                              hipStream_t stream) {
    const float* xb = (const float*)d_in[0];   // [4096, 256] fp32
    const float* wt = (const float*)d_in[1];   // [16384, 256] fp32
    int* out = (int*)d_out;                    // [4096, 2] int32

    char* ws = (char*)d_ws;
    _Float16* xh  = (_Float16*)(ws);                                   // 2 MB
    _Float16* wh  = (_Float16*)(ws + (size_t)2 * 1024 * 1024);         // 8 MB
    float*    wsq = (float*)(ws + (size_t)10 * 1024 * 1024);           // 64 KB
    u64*    plist = (u64*)(ws + (size_t)11 * 1024 * 1024);             // 16 MB

    som_split<<<(B_ROWS * 32 + M_COLS * 32) / 256, 256, 0, stream>>>(xb, wt, xh, wh, wsq);
    som_main<<<BM * NCHUNK / 4, 256, 0, stream>>>(xh, wh, wsq, plist);
    som_rescore<<<B_ROWS / 4, 256, 0, stream>>>(xb, wt, wsq, plist, out);
}